// Round 1
// 1329.506 us; speedup vs baseline: 1.1718x; 1.1718x over previous
//
#include <hip/hip_runtime.h>

typedef __attribute__((ext_vector_type(8))) short s16x8;
typedef __attribute__((ext_vector_type(4))) short s16x4;
typedef __attribute__((ext_vector_type(4))) float f32x4;

static constexpr int B_ = 4;
static constexpr int S_ = 1024;
static constexpr int D_ = 1024;
static constexpr int H_ = 16;
static constexpr int DH_ = 64;
static constexpr float SCALE = 0.125f;  // 1/sqrt(64)

__device__ __forceinline__ float sigm(float x) { return 1.0f / (1.0f + __expf(-x)); }

// fp32 -> bf16 round-to-nearest-even (values are finite; NaN path irrelevant)
__device__ __forceinline__ unsigned short f2b(float f) {
    unsigned int u = __float_as_uint(f);
    return (unsigned short)((u + 0x7FFFu + ((u >> 16) & 1u)) >> 16);
}
__device__ __forceinline__ float b2f(unsigned short u) {
    return __uint_as_float(((unsigned int)u) << 16);
}

// ---------------------------------------------------------------------------
// Cast hs [4096,1024] fp32 -> bf16. 4 elems/thread, grid 4096 x 256.
// ---------------------------------------------------------------------------
__global__ __launch_bounds__(256) void cast_bf16(const float* __restrict__ in,
                                                 short* __restrict__ out) {
    const size_t idx = (size_t)blockIdx.x * 256 + threadIdx.x;
    float4 x = *(const float4*)(in + idx * 4);
    s16x4 o;
    o[0] = (short)f2b(x.x); o[1] = (short)f2b(x.y);
    o[2] = (short)f2b(x.z); o[3] = (short)f2b(x.w);
    *(s16x4*)(out + idx * 4) = o;
}

// ---------------------------------------------------------------------------
// Transpose + cast Wq/Wk/Wv [K=1024][N=1024] fp32 -> Wt[mat][N][K] bf16.
// grid (32,32,3), 32x32 tile via LDS.
// ---------------------------------------------------------------------------
__global__ __launch_bounds__(256) void transpose_cast_w(
    const float* __restrict__ Wq, const float* __restrict__ Wk,
    const float* __restrict__ Wv, short* __restrict__ Wt) {
    __shared__ float tile[32][33];
    const float* W = (blockIdx.z == 0) ? Wq : (blockIdx.z == 1) ? Wk : Wv;
    short* dst = Wt + (size_t)blockIdx.z * 1024 * 1024;
    const int t = threadIdx.x, tx = t & 31, ty = t >> 5;  // ty 0..7
    const int n0 = blockIdx.x * 32, k0 = blockIdx.y * 32;
    #pragma unroll
    for (int r = 0; r < 4; ++r)
        tile[ty + 8 * r][tx] = W[(size_t)(k0 + ty + 8 * r) * 1024 + n0 + tx];
    __syncthreads();
    #pragma unroll
    for (int r = 0; r < 4; ++r)
        dst[(size_t)(n0 + ty + 8 * r) * 1024 + k0 + tx] =
            (short)f2b(tile[tx][ty + 8 * r]);
}

// ---------------------------------------------------------------------------
// QKV projection with bf16 MFMA: C[4096,3072] = hsb @ W + b, scattered to
// q/k/v bf16 [B,H,S,DH]. grid (48,64): bx>>4 picks matrix, 64x64 tile/block,
// 4 waves x (16 rows x 64 cols), K-loop 32/step, B^T-form fragment loads.
// ---------------------------------------------------------------------------
__global__ __launch_bounds__(256) void gemm_qkv_mfma(
    const short* __restrict__ hsb, const short* __restrict__ Wt,
    const float* __restrict__ bq, const float* __restrict__ bk,
    const float* __restrict__ bv,
    short* __restrict__ qb, short* __restrict__ kb, short* __restrict__ vb) {
    const int t = threadIdx.x;
    const int w = t >> 6, l = t & 63;
    const int lg = l >> 4, ll = l & 15;
    const int bx = blockIdx.x, by = blockIdx.y;
    const int mat = bx >> 4;
    const int ncol0 = (bx & 15) * 64;
    const float* bias = (mat == 0) ? bq : (mat == 1) ? bk : bv;
    short* dst = (mat == 0) ? qb : (mat == 1) ? kb : vb;
    const short* Wm = Wt + (size_t)mat * 1024 * 1024;

    const short* Aptr = hsb + (size_t)(by * 64 + w * 16 + ll) * 1024 + lg * 8;
    const short* Bptr = Wm + (size_t)(ncol0 + ll) * 1024 + lg * 8;

    f32x4 zero = {0.f, 0.f, 0.f, 0.f};
    f32x4 acc[4] = {zero, zero, zero, zero};
    for (int k0 = 0; k0 < 1024; k0 += 32) {
        s16x8 a = *(const s16x8*)(Aptr + k0);
        #pragma unroll
        for (int jt = 0; jt < 4; ++jt) {
            s16x8 b = *(const s16x8*)(Bptr + (size_t)jt * 16 * 1024 + k0);
            acc[jt] = __builtin_amdgcn_mfma_f32_16x16x32_bf16(a, b, acc[jt], 0, 0, 0);
        }
    }
    const int h = bx & 15;
    #pragma unroll
    for (int jt = 0; jt < 4; ++jt) {
        const int d = jt * 16 + ll;
        const float bsum = bias[ncol0 + d];
        #pragma unroll
        for (int r = 0; r < 4; ++r) {
            const int m = by * 64 + w * 16 + lg * 4 + r;
            const int bb = m >> 10, ss = m & (S_ - 1);
            dst[(((size_t)(bb * H_ + h)) * S_ + ss) * DH_ + d] =
                (short)f2b(acc[jt][r] + bsum);
        }
    }
}

// ---------------------------------------------------------------------------
// Transpose v [bh][S][DH] -> vt [bh][DH][S] (bf16). grid (16,64).
// ---------------------------------------------------------------------------
__global__ __launch_bounds__(256) void transpose_v(const short* __restrict__ v,
                                                   short* __restrict__ vt) {
    __shared__ short tile[64][72];
    const int bh = blockIdx.y, s0 = blockIdx.x * 64;
    const int t = threadIdx.x, tx = t & 63, ty = t >> 6;  // ty 0..3
    const short* src = v + (size_t)bh * S_ * DH_;
    short* dst = vt + (size_t)bh * DH_ * S_;
    #pragma unroll
    for (int r = 0; r < 16; ++r)
        tile[ty + 4 * r][tx] = src[(size_t)(s0 + ty + 4 * r) * DH_ + tx];
    __syncthreads();
    #pragma unroll
    for (int r = 0; r < 16; ++r)
        dst[(size_t)(ty + 4 * r) * S_ + s0 + tx] = tile[tx][ty + 4 * r];
}

// ---------------------------------------------------------------------------
// cq/ck projection (fp32, unchanged): [4096,1024] @ [1024,64] + bias.
// ---------------------------------------------------------------------------
__global__ __launch_bounds__(256) void gemm_cqck(
    const float* __restrict__ A,
    const float* __restrict__ Wcq, const float* __restrict__ bcq,
    const float* __restrict__ Wck, const float* __restrict__ bck,
    float* __restrict__ cqo, float* __restrict__ cko) {
    __shared__ float At[32][64];
    __shared__ float Bs[32][64];
    const int t = threadIdx.x;
    const int bx = blockIdx.x;
    const int by = blockIdx.y;
    const float* W = bx ? Wck : Wcq;
    const float* bi = bx ? bck : bcq;
    float* out = bx ? cko : cqo;

    const int tx = t & 15, ty = t >> 4;
    const int ar = t >> 3, ac = (t & 7) << 2;
    const int br = t >> 4, bc = (t & 15) << 2;

    float acc[4][4] = {};
    for (int k0 = 0; k0 < D_; k0 += 32) {
        float4 a0 = *(const float4*)(A + (size_t)(by * 64 + ar) * D_ + k0 + ac);
        float4 a1 = *(const float4*)(A + (size_t)(by * 64 + ar + 32) * D_ + k0 + ac);
        float4 b0 = *(const float4*)(W + (size_t)(k0 + br) * DH_ + bc);
        float4 b1 = *(const float4*)(W + (size_t)(k0 + br + 16) * DH_ + bc);
        At[ac + 0][ar] = a0.x; At[ac + 1][ar] = a0.y;
        At[ac + 2][ar] = a0.z; At[ac + 3][ar] = a0.w;
        At[ac + 0][ar + 32] = a1.x; At[ac + 1][ar + 32] = a1.y;
        At[ac + 2][ar + 32] = a1.z; At[ac + 3][ar + 32] = a1.w;
        *(float4*)(&Bs[br][bc]) = b0;
        *(float4*)(&Bs[br + 16][bc]) = b1;
        __syncthreads();
        #pragma unroll
        for (int kk = 0; kk < 32; ++kk) {
            float4 avv = *(const float4*)(&At[kk][ty * 4]);
            float4 bvv = *(const float4*)(&Bs[kk][tx * 4]);
            const float* av = reinterpret_cast<const float*>(&avv);
            const float* bv = reinterpret_cast<const float*>(&bvv);
            #pragma unroll
            for (int i = 0; i < 4; ++i)
                #pragma unroll
                for (int j = 0; j < 4; ++j)
                    acc[i][j] = fmaf(av[i], bv[j], acc[i][j]);
        }
        __syncthreads();
    }
    #pragma unroll
    for (int i = 0; i < 4; ++i) {
        int m = by * 64 + ty * 4 + i;
        float4 ov;
        ((float*)&ov)[0] = acc[i][0] + bi[tx * 4 + 0];
        ((float*)&ov)[1] = acc[i][1] + bi[tx * 4 + 1];
        ((float*)&ov)[2] = acc[i][2] + bi[tx * 4 + 2];
        ((float*)&ov)[3] = acc[i][3] + bi[tx * 4 + 3];
        *(float4*)(out + (size_t)m * DH_ + tx * 4) = ov;
    }
}

// ---------------------------------------------------------------------------
// lambda_context[b,h,s] = 1 - sigm(cq.w_lqc + q.w_lqq) - sigm(ck.w_lkc + k.w_lkk)
// q,k now bf16.
// ---------------------------------------------------------------------------
__global__ __launch_bounds__(256) void lambda_kernel(
    const short* __restrict__ q, const short* __restrict__ k,
    const float* __restrict__ cq, const float* __restrict__ ck,
    const float* __restrict__ wlqc, const float* __restrict__ wlqq,
    const float* __restrict__ wlkc, const float* __restrict__ wlkk,
    float* __restrict__ lam) {
    __shared__ float w[4][64];
    const int t = threadIdx.x;
    if (t < 64) { w[0][t] = wlqc[t]; w[1][t] = wlqq[t]; w[2][t] = wlkc[t]; w[3][t] = wlkk[t]; }
    __syncthreads();
    const int idx = blockIdx.x * 256 + t;        // (b*H+h)*S + s
    const int ssi = idx & (S_ - 1);
    const int b = idx >> 14;
    const short* qrow = q + (size_t)idx * DH_;
    const short* krow = k + (size_t)idx * DH_;
    const float* cqrow = cq + ((size_t)b * S_ + ssi) * DH_;
    const float* ckrow = ck + ((size_t)b * S_ + ssi) * DH_;
    float s1 = 0.f, s2 = 0.f, s3 = 0.f, s4 = 0.f;
    #pragma unroll
    for (int d0 = 0; d0 < DH_; d0 += 8) {
        s16x8 qa = *(const s16x8*)(qrow + d0);
        s16x8 ka = *(const s16x8*)(krow + d0);
        #pragma unroll
        for (int e = 0; e < 8; ++e) {
            s1 = fmaf(cqrow[d0 + e], w[0][d0 + e], s1);
            s2 = fmaf(b2f((unsigned short)qa[e]), w[1][d0 + e], s2);
            s3 = fmaf(ckrow[d0 + e], w[2][d0 + e], s3);
            s4 = fmaf(b2f((unsigned short)ka[e]), w[3][d0 + e], s4);
        }
    }
    lam[idx] = 1.0f - sigm(s1 + s2) - sigm(s3 + s4);
}

// ---------------------------------------------------------------------------
// Quasi scores (fp32, unchanged): qs = sigmoid(cq.ck * scale + mask), z = b.
// ---------------------------------------------------------------------------
__global__ __launch_bounds__(256) void score64(
    const float* __restrict__ Abase, const float* __restrict__ Bbase,
    float* __restrict__ Obase, const float* __restrict__ mask,
    int bshift, int do_sig) {
    __shared__ float At[64][64];
    __shared__ float Bt[64][64];
    const int z = blockIdx.z;
    const int jt = blockIdx.x, it = blockIdx.y;
    const float* Am = Abase + (size_t)z * S_ * DH_;
    const float* Bm = Bbase + (size_t)z * S_ * DH_;
    float* Om = Obase + (size_t)z * S_ * S_;
    const int b = z >> bshift;
    const int t = threadIdx.x;
    const int r = t >> 2, c0 = (t & 3) << 4;
    #pragma unroll
    for (int u = 0; u < 4; ++u) {
        float4 av = *(const float4*)(Am + (size_t)(it * 64 + r) * DH_ + c0 + u * 4);
        float4 bv = *(const float4*)(Bm + (size_t)(jt * 64 + r) * DH_ + c0 + u * 4);
        At[c0 + u * 4 + 0][r] = av.x; At[c0 + u * 4 + 1][r] = av.y;
        At[c0 + u * 4 + 2][r] = av.z; At[c0 + u * 4 + 3][r] = av.w;
        Bt[c0 + u * 4 + 0][r] = bv.x; Bt[c0 + u * 4 + 1][r] = bv.y;
        Bt[c0 + u * 4 + 2][r] = bv.z; Bt[c0 + u * 4 + 3][r] = bv.w;
    }
    __syncthreads();
    const int tx = t & 15, ty = t >> 4;
    float acc[4][4] = {};
    #pragma unroll 8
    for (int d = 0; d < 64; ++d) {
        float4 avv = *(const float4*)(&At[d][ty * 4]);
        float4 bvv = *(const float4*)(&Bt[d][tx * 4]);
        const float* av = reinterpret_cast<const float*>(&avv);
        const float* bv = reinterpret_cast<const float*>(&bvv);
        #pragma unroll
        for (int i = 0; i < 4; ++i)
            #pragma unroll
            for (int j = 0; j < 4; ++j)
                acc[i][j] = fmaf(av[i], bv[j], acc[i][j]);
    }
    #pragma unroll
    for (int i = 0; i < 4; ++i) {
        const int ig = it * 64 + ty * 4 + i;
        float4 ov;
        #pragma unroll
        for (int j = 0; j < 4; ++j) {
            const int jg = jt * 64 + tx * 4 + j;
            float val = acc[i][j] * SCALE + mask[b * S_ + jg];
            if (do_sig) val = sigm(val);
            ((float*)&ov)[j] = val;
        }
        *(float4*)(&Om[(size_t)ig * S_ + jt * 64 + tx * 4]) = ov;
    }
}

// ---------------------------------------------------------------------------
// Fused attention: per (bh, 16-row tile) block, 4 waves x 256-col slices.
// QK^T (MFMA, scores in regs) -> cross-wave softmax -> write attn/quasi/newp
// -> bf16(newp) to LDS -> PV (MFMA over wave's 256-key slice) -> cross-wave
// ctx reduce -> coalesced fp32 ctx store.
// ---------------------------------------------------------------------------
__global__ __launch_bounds__(256) void attn_fused(
    const short* __restrict__ qb, const short* __restrict__ kb,
    const short* __restrict__ vt, const float* __restrict__ qs,
    const float* __restrict__ lam, const float* __restrict__ mask,
    float* __restrict__ attn, float* __restrict__ quasi,
    float* __restrict__ newp, float* __restrict__ ctx) {
    __shared__ short Plds[16][1032];        // pad 1024->1032: breaks 2KB-stride bank conflict
    __shared__ float ctxred[4][16][64];
    __shared__ float redm[4][16];
    __shared__ float reds[4][16];

    const int t = threadIdx.x;
    const int w = t >> 6, l = t & 63;
    const int lg = l >> 4, ll = l & 15;
    const int i0 = blockIdx.x * 16;
    const int bh = blockIdx.y;
    const int b = bh >> 4, h = bh & 15;

    // ---- QK^T: 16 rows x 256 cols per wave, K=64 ----
    const short* qp = qb + (((size_t)bh * S_) + i0 + ll) * DH_ + lg * 8;
    s16x8 aq0 = *(const s16x8*)(qp);
    s16x8 aq1 = *(const s16x8*)(qp + 32);

    f32x4 acc[16];
    const short* kp0 = kb + (((size_t)bh * S_) + w * 256 + ll) * DH_ + lg * 8;
    #pragma unroll
    for (int jt = 0; jt < 16; ++jt) {
        const short* kp = kp0 + (size_t)jt * 16 * DH_;
        s16x8 b0 = *(const s16x8*)(kp);
        s16x8 b1 = *(const s16x8*)(kp + 32);
        f32x4 c = {0.f, 0.f, 0.f, 0.f};
        c = __builtin_amdgcn_mfma_f32_16x16x32_bf16(aq0, b0, c, 0, 0, 0);
        c = __builtin_amdgcn_mfma_f32_16x16x32_bf16(aq1, b1, c, 0, 0, 0);
        acc[jt] = c;
    }

    // ---- scale + mask, per-row max (C layout: col=ll, row=lg*4+reg) ----
    float rmax[4] = {-3.0e38f, -3.0e38f, -3.0e38f, -3.0e38f};
    #pragma unroll
    for (int jt = 0; jt < 16; ++jt) {
        float mk = mask[b * S_ + w * 256 + jt * 16 + ll];
        #pragma unroll
        for (int r = 0; r < 4; ++r) {
            float sv = acc[jt][r] * SCALE + mk;
            acc[jt][r] = sv;
            rmax[r] = fmaxf(rmax[r], sv);
        }
    }
    #pragma unroll
    for (int off = 1; off < 16; off <<= 1)
        #pragma unroll
        for (int r = 0; r < 4; ++r)
            rmax[r] = fmaxf(rmax[r], __shfl_xor(rmax[r], off));
    if (ll == 0) {
        #pragma unroll
        for (int r = 0; r < 4; ++r) redm[w][lg * 4 + r] = rmax[r];
    }
    __syncthreads();
    #pragma unroll
    for (int r = 0; r < 4; ++r) {
        const int row = lg * 4 + r;
        rmax[r] = fmaxf(fmaxf(redm[0][row], redm[1][row]),
                        fmaxf(redm[2][row], redm[3][row]));
    }

    // ---- exp + row sum ----
    float rsum[4] = {0.f, 0.f, 0.f, 0.f};
    #pragma unroll
    for (int jt = 0; jt < 16; ++jt)
        #pragma unroll
        for (int r = 0; r < 4; ++r) {
            float e = __expf(acc[jt][r] - rmax[r]);
            acc[jt][r] = e;
            rsum[r] += e;
        }
    #pragma unroll
    for (int off = 1; off < 16; off <<= 1)
        #pragma unroll
        for (int r = 0; r < 4; ++r)
            rsum[r] += __shfl_xor(rsum[r], off);
    if (ll == 0) {
        #pragma unroll
        for (int r = 0; r < 4; ++r) reds[w][lg * 4 + r] = rsum[r];
    }
    __syncthreads();

    float inv[4], lamr[4];
    size_t obase[4], qsbase[4];
    #pragma unroll
    for (int r = 0; r < 4; ++r) {
        const int row = lg * 4 + r;
        inv[r] = 1.0f / (reds[0][row] + reds[1][row] + reds[2][row] + reds[3][row]);
        const int rg = i0 + row;
        lamr[r] = lam[(size_t)bh * S_ + rg];
        obase[r] = ((size_t)bh * S_ + rg) * S_;
        qsbase[r] = ((size_t)b * S_ + rg) * S_;
    }

    // ---- probs / quasi / new, stage bf16(new) to LDS ----
    #pragma unroll
    for (int jt = 0; jt < 16; ++jt) {
        const int col = w * 256 + jt * 16 + ll;
        #pragma unroll
        for (int r = 0; r < 4; ++r) {
            float p = acc[jt][r] * inv[r];
            float qv = qs[qsbase[r] + col];
            float qp_ = lamr[r] * qv;
            float np = p + qp_;
            attn[obase[r] + col] = p;
            quasi[obase[r] + col] = qp_;
            newp[obase[r] + col] = np;
            Plds[lg * 4 + r][col] = (short)f2b(np);
        }
    }
    __syncthreads();

    // ---- PV: wave handles key slice [w*256, w*256+256) ----
    f32x4 zero = {0.f, 0.f, 0.f, 0.f};
    f32x4 cacc[4] = {zero, zero, zero, zero};
    const short* vp0 = vt + ((size_t)bh * DH_ + ll) * S_ + w * 256 + lg * 8;
    #pragma unroll
    for (int ks = 0; ks < 8; ++ks) {
        s16x8 a = *(const s16x8*)(&Plds[ll][w * 256 + ks * 32 + lg * 8]);
        #pragma unroll
        for (int jd = 0; jd < 4; ++jd) {
            s16x8 bv = *(const s16x8*)(vp0 + (size_t)jd * 16 * S_ + ks * 32);
            cacc[jd] = __builtin_amdgcn_mfma_f32_16x16x32_bf16(a, bv, cacc[jd], 0, 0, 0);
        }
    }
    #pragma unroll
    for (int jd = 0; jd < 4; ++jd)
        #pragma unroll
        for (int r = 0; r < 4; ++r)
            ctxred[w][lg * 4 + r][jd * 16 + ll] = cacc[jd][r];
    __syncthreads();

    {
        const int r = t >> 4, c = (t & 15) * 4;
        float4 s0 = *(const float4*)&ctxred[0][r][c];
        float4 s1 = *(const float4*)&ctxred[1][r][c];
        float4 s2 = *(const float4*)&ctxred[2][r][c];
        float4 s3 = *(const float4*)&ctxred[3][r][c];
        float4 o;
        o.x = s0.x + s1.x + s2.x + s3.x;
        o.y = s0.y + s1.y + s2.y + s3.y;
        o.z = s0.z + s1.z + s2.z + s3.z;
        o.w = s0.w + s1.w + s2.w + s3.w;
        *(float4*)(ctx + ((size_t)b * S_ + i0 + r) * D_ + h * DH_ + c) = o;
    }
}

extern "C" void kernel_launch(void* const* d_in, const int* in_sizes, int n_in,
                              void* d_out, int out_size, void* d_ws, size_t ws_size,
                              hipStream_t stream) {
    const float* hs   = (const float*)d_in[0];
    const float* mask = (const float*)d_in[1];
    const float* ce   = (const float*)d_in[2];
    const float* Wq   = (const float*)d_in[3];
    const float* bq   = (const float*)d_in[4];
    const float* Wk   = (const float*)d_in[5];
    const float* bk   = (const float*)d_in[6];
    const float* Wv   = (const float*)d_in[7];
    const float* bv   = (const float*)d_in[8];
    const float* Wcq  = (const float*)d_in[9];
    const float* bcq  = (const float*)d_in[10];
    const float* Wck  = (const float*)d_in[11];
    const float* bck  = (const float*)d_in[12];
    const float* wlqc = (const float*)d_in[13];
    const float* wlqq = (const float*)d_in[14];
    const float* wlkc = (const float*)d_in[15];
    const float* wlkk = (const float*)d_in[16];

    float* out   = (float*)d_out;
    float* ctx   = out;                                   // [B,S,D]
    float* newp  = ctx  + (size_t)B_ * S_ * D_;           // [B,H,S,S]
    float* attn  = newp + (size_t)B_ * H_ * S_ * S_;      // [B,H,S,S]
    float* quasi = attn + (size_t)B_ * H_ * S_ * S_;      // [B,H,S,S]

    // workspace: bf16 (short) regions first, then fp32. 64.25 MB total.
    short* hsb = (short*)d_ws;                            // [4096,1024] bf16
    short* Wt  = hsb + (size_t)4096 * 1024;               // [3,1024,1024] bf16 (W^T)
    short* qb  = Wt  + (size_t)3 * 1024 * 1024;           // [B,H,S,DH] bf16
    short* kb  = qb  + (size_t)4096 * 1024;
    short* vb  = kb  + (size_t)4096 * 1024;               // [B,H,S,DH] bf16
    short* vtb = vb  + (size_t)4096 * 1024;               // [B,H,DH,S] bf16
    float* cq  = (float*)(vtb + (size_t)4096 * 1024);     // [B,S,DH] fp32
    float* ck  = cq + (size_t)B_ * S_ * DH_;
    float* lamp = ck + (size_t)B_ * S_ * DH_;             // [B,H,S]
    float* qsp  = lamp + (size_t)B_ * H_ * S_;            // [B,S,S]

    cast_bf16<<<dim3(4096), 256, 0, stream>>>(hs, hsb);
    transpose_cast_w<<<dim3(32, 32, 3), 256, 0, stream>>>(Wq, Wk, Wv, Wt);
    gemm_qkv_mfma<<<dim3(48, 64), 256, 0, stream>>>(hsb, Wt, bq, bk, bv, qb, kb, vb);
    transpose_v<<<dim3(16, 64), 256, 0, stream>>>(vb, vtb);
    gemm_cqck<<<dim3(2, 64), 256, 0, stream>>>(ce, Wcq, bcq, Wck, bck, cq, ck);
    lambda_kernel<<<256, 256, 0, stream>>>(qb, kb, cq, ck, wlqc, wlqq, wlkc, wlkk, lamp);
    score64<<<dim3(16, 16, 4), 256, 0, stream>>>(cq, ck, qsp, mask, 0, 1);
    attn_fused<<<dim3(64, 64), 256, 0, stream>>>(qb, kb, vtb, qsp, lamp, mask,
                                                 attn, quasi, newp, ctx);
}